// Round 1
// baseline (669.629 us; speedup 1.0000x reference)
//
#include <hip/hip_runtime.h>
#include <math.h>

#define NN  50000
#define NE  1600000
#define NEP 500000
#define DIN 64
#define DE  32

// ---------------- degree histogram ----------------
__global__ __launch_bounds__(256) void k_deg(const int* __restrict__ src,
                                             const int* __restrict__ dst,
                                             float* __restrict__ ds,
                                             float* __restrict__ dd) {
    int i = blockIdx.x * 256 + threadIdx.x;
    if (i < NE) {
        atomicAdd(&ds[src[i]], 1.0f);
        atomicAdd(&dd[dst[i]], 1.0f);
    }
}

// ---------------- norms: deg -> clamp(.,1)^-0.5 (in place) ----------------
__global__ __launch_bounds__(256) void k_norm(float* __restrict__ ns,
                                              float* __restrict__ nd) {
    int i = blockIdx.x * 256 + threadIdx.x;
    if (i < NN) {
        ns[i] = rsqrtf(fmaxf(ns[i], 1.0f));
        nd[i] = rsqrtf(fmaxf(nd[i], 1.0f));
    }
}

// ---------------- xw1[r][c] = ns[r] * (x[r] @ W1)[c]  (64 -> 32) ----------------
// 256 threads = 8 rows x 32 cols per block; NN % 8 == 0 so no tail.
__global__ __launch_bounds__(256) void k_xw1(const float* __restrict__ x,
                                             const float* __restrict__ W1,
                                             const float* __restrict__ ns,
                                             float* __restrict__ xw1) {
    __shared__ float sW[DIN * DE];
    int t = threadIdx.x;
    for (int i = t; i < DIN * DE; i += 256) sW[i] = W1[i];
    __syncthreads();
    int r = blockIdx.x * 8 + (t >> 5);
    int c = t & 31;
    const float* xr = x + (size_t)r * DIN;
    float acc = 0.f;
#pragma unroll
    for (int k = 0; k < DIN; k++) acc += xr[k] * sW[k * DE + c];
    xw1[r * DE + c] = acc * ns[r];
}

// ---------------- edge scatter: agg[dst] += msg[src] (32 f32 per edge) ----------------
// 32 consecutive threads per edge: coalesced 128B gather + 32 coalesced atomics.
__global__ __launch_bounds__(256) void k_scatter(const int* __restrict__ src,
                                                 const int* __restrict__ dst,
                                                 const float* __restrict__ msg,
                                                 float* __restrict__ agg) {
    int t = blockIdx.x * 256 + threadIdx.x;
    int e = t >> 5;
    int c = t & 31;
    if (e < NE) {
        int s = src[e];
        int d = dst[e];
        atomicAdd(&agg[d * DE + c], msg[s * DE + c]);
    }
}

// ---------------- h1s = relu(nd*agg1 + b1) * ns ; zero agg1 for reuse as agg2 ----------------
__global__ __launch_bounds__(256) void k_h1(float* __restrict__ agg1,
                                            const float* __restrict__ nd,
                                            const float* __restrict__ b1,
                                            const float* __restrict__ ns,
                                            float* __restrict__ h1s) {
    int i = blockIdx.x * 256 + threadIdx.x;   // NN*DE threads exactly
    int r = i >> 5;
    int c = i & 31;
    float v = fmaxf(nd[r] * agg1[i] + b1[c], 0.0f) * ns[r];
    h1s[i] = v;
    agg1[i] = 0.0f;   // becomes zeroed agg2 buffer for the next scatter
}

// ---------------- epilogue: h2 = (nd*agg2)@W2 + b2; mu/sigma/z ----------------
// 256 threads = 4 rows x 64 cols; NN % 4 == 0 so no tail -> __syncthreads safe.
__global__ __launch_bounds__(256) void k_final(const float* __restrict__ agg2,
                                               const float* __restrict__ nd,
                                               const float* __restrict__ W2,
                                               const float* __restrict__ b2,
                                               const float* __restrict__ eps,
                                               float* __restrict__ out_mu,
                                               float* __restrict__ out_sigma,
                                               float* __restrict__ z) {
    __shared__ float sW[DE * 64];
    __shared__ float sA[4][DE];
    __shared__ float sMu[4][DE];
    int t = threadIdx.x;
    for (int i = t; i < DE * 64; i += 256) sW[i] = W2[i];
    int rr = t >> 6;
    int c  = t & 63;
    int r  = blockIdx.x * 4 + rr;
    if (c < DE) sA[rr][c] = nd[r] * agg2[r * DE + c];
    __syncthreads();
    float acc = b2[c];
#pragma unroll
    for (int k = 0; k < DE; k++) acc += sA[rr][k] * sW[k * 64 + c];
    if (c < DE) {
        out_mu[r * DE + c] = acc;
        sMu[rr][c] = acc;
    }
    __syncthreads();
    if (c >= DE) {
        int cc = c - DE;
        float sg = expf(0.5f * acc);          // sigma = exp(log_var/2)
        out_sigma[r * DE + cc] = sg;
        z[r * DE + cc] = sMu[rr][cc] + sg * eps[r * DE + cc];
    }
}

// ---------------- edge dot: out[e] = sum_c z[u][c]*z[v][c] ----------------
// 8 lanes per edge, float4 loads, shfl-xor reduce within the 8-lane group.
__global__ __launch_bounds__(256) void k_dot(const float* __restrict__ z,
                                             const int* __restrict__ u,
                                             const int* __restrict__ v,
                                             float* __restrict__ out) {
    int t = blockIdx.x * 256 + threadIdx.x;
    int e = t >> 3;
    int l = t & 7;
    if (e < NEP) {
        int a = u[e];
        int b = v[e];
        float4 za = ((const float4*)z)[a * 8 + l];
        float4 zb = ((const float4*)z)[b * 8 + l];
        float s = za.x * zb.x + za.y * zb.y + za.z * zb.z + za.w * zb.w;
        s += __shfl_xor(s, 1);
        s += __shfl_xor(s, 2);
        s += __shfl_xor(s, 4);
        if (l == 0) out[e] = s;
    }
}

extern "C" void kernel_launch(void* const* d_in, const int* in_sizes, int n_in,
                              void* d_out, int out_size, void* d_ws, size_t ws_size,
                              hipStream_t stream) {
    const float* x    = (const float*)d_in[0];
    const float* W1   = (const float*)d_in[1];
    const float* b1   = (const float*)d_in[2];
    const float* W2   = (const float*)d_in[3];
    const float* b2   = (const float*)d_in[4];
    const float* eps  = (const float*)d_in[5];
    const int*   esrc = (const int*)d_in[6];
    const int*   edst = (const int*)d_in[7];
    const int*   psrc = (const int*)d_in[8];
    const int*   pdst = (const int*)d_in[9];
    const int*   gsrc = (const int*)d_in[10];
    const int*   gdst = (const int*)d_in[11];

    float* out = (float*)d_out;
    float* pos = out;                      // [NEP]
    float* neg = out + NEP;                // [NEP]
    float* mu  = out + 2 * NEP;            // [NN*DE]
    float* sg  = out + 2 * NEP + NN * DE;  // [NN*DE]

    // workspace layout (floats):
    // [0,NN)        deg_src -> ns
    // [NN,2NN)      deg_dst -> nd
    // [2NN,34NN)    B: agg1 -> (zeroed) -> agg2
    // [34NN,66NN)   A: xw1 -> h1s
    // [66NN,98NN)   Z
    float* ws  = (float*)d_ws;
    float* vns = ws;
    float* vnd = ws + NN;
    float* B   = ws + 2 * NN;
    float* A   = ws + 2 * NN + 32 * NN;
    float* Z   = ws + 2 * NN + 64 * NN;

    // zero degrees + agg1 in one shot ([0, 34NN))
    hipMemsetAsync(ws, 0, (size_t)(34 * NN) * sizeof(float), stream);

    k_deg<<<(NE + 255) / 256, 256, 0, stream>>>(esrc, edst, vns, vnd);
    k_norm<<<(NN + 255) / 256, 256, 0, stream>>>(vns, vnd);
    k_xw1<<<NN / 8, 256, 0, stream>>>(x, W1, vns, A);
    k_scatter<<<(NE * 32) / 256, 256, 0, stream>>>(esrc, edst, A, B);
    k_h1<<<(NN * DE) / 256, 256, 0, stream>>>(B, vnd, b1, vns, A);
    k_scatter<<<(NE * 32) / 256, 256, 0, stream>>>(esrc, edst, A, B);
    k_final<<<NN / 4, 256, 0, stream>>>(B, vnd, W2, b2, eps, mu, sg, Z);
    k_dot<<<(NEP * 8) / 256, 256, 0, stream>>>(Z, psrc, pdst, pos);
    k_dot<<<(NEP * 8) / 256, 256, 0, stream>>>(Z, gsrc, gdst, neg);
}

// Round 2
// 602.267 us; speedup vs baseline: 1.1118x; 1.1118x over previous
//
#include <hip/hip_runtime.h>
#include <math.h>

#define NN  50000
#define NE  1600000
#define NEP 500000
#define DIN 64
#define DE  32

// ---------------- degree histogram (int) ----------------
__global__ __launch_bounds__(256) void k_deg(const int* __restrict__ src,
                                             const int* __restrict__ dst,
                                             int* __restrict__ degs,
                                             int* __restrict__ degd) {
    int i = blockIdx.x * 256 + threadIdx.x;
    if (i < NE) {
        atomicAdd(&degs[src[i]], 1);
        atomicAdd(&degd[dst[i]], 1);
    }
}

// ---------------- norms ----------------
__global__ __launch_bounds__(256) void k_norm(const int* __restrict__ degs,
                                              const int* __restrict__ degd,
                                              float* __restrict__ ns,
                                              float* __restrict__ nd) {
    int i = blockIdx.x * 256 + threadIdx.x;
    if (i < NN) {
        ns[i] = rsqrtf(fmaxf((float)degs[i], 1.0f));
        nd[i] = rsqrtf(fmaxf((float)degd[i], 1.0f));
    }
}

// ---------------- single-block exclusive scan of in-degrees -> rowptr & cursor ----------------
__global__ __launch_bounds__(1024) void k_scan(const int* __restrict__ deg,
                                               int* __restrict__ rowptr,
                                               int* __restrict__ cursor) {
    __shared__ int part[1024];
    int t = threadIdx.x;
    int beg = t * 49;
    int end = beg + 49; if (end > NN) end = NN;
    int s = 0;
    for (int i = beg; i < end; i++) s += deg[i];
    part[t] = s;
    __syncthreads();
    // Hillis-Steele inclusive scan over 1024 partials
    for (int off = 1; off < 1024; off <<= 1) {
        int v = (t >= off) ? part[t - off] : 0;
        __syncthreads();
        part[t] += v;
        __syncthreads();
    }
    int run = (t == 0) ? 0 : part[t - 1];
    for (int i = beg; i < end; i++) {
        rowptr[i] = run;
        cursor[i] = run;
        run += deg[i];
    }
    if (t == 0) rowptr[NN] = NE;
}

// ---------------- CSR fill: 1 int atomic per edge ----------------
__global__ __launch_bounds__(256) void k_fill(const int* __restrict__ src,
                                              const int* __restrict__ dst,
                                              int* __restrict__ cursor,
                                              int* __restrict__ csr) {
    int e = blockIdx.x * 256 + threadIdx.x;
    if (e < NE) {
        int p = atomicAdd(&cursor[dst[e]], 1);
        csr[p] = src[e];
    }
}

// ---------------- xw1[r][c] = ns[r] * (x[r] @ W1)[c]  (64 -> 32) ----------------
__global__ __launch_bounds__(256) void k_xw1(const float* __restrict__ x,
                                             const float* __restrict__ W1,
                                             const float* __restrict__ ns,
                                             float* __restrict__ xw1) {
    __shared__ float sW[DIN * DE];
    int t = threadIdx.x;
    for (int i = t; i < DIN * DE; i += 256) sW[i] = W1[i];
    __syncthreads();
    int r = blockIdx.x * 8 + (t >> 5);
    int c = t & 31;
    const float* xr = x + (size_t)r * DIN;
    float acc = 0.f;
#pragma unroll
    for (int k = 0; k < DIN; k++) acc += xr[k] * sW[k * DE + c];
    xw1[r * DE + c] = acc * ns[r];
}

// ---------------- CSR gather: agg[r] = sum over incident edges of msg[src] ----------------
// 8 lanes per node, float4 per lane. L1=true fuses relu(nd*agg+b1)*ns; else out = nd*agg.
template <bool L1>
__global__ __launch_bounds__(256) void k_gather(const int* __restrict__ rowptr,
                                                const int* __restrict__ csr,
                                                const float4* __restrict__ msg,
                                                const float* __restrict__ nd,
                                                const float* __restrict__ b1,
                                                const float* __restrict__ ns,
                                                float4* __restrict__ out) {
    int t = blockIdx.x * 256 + threadIdx.x;
    int r = t >> 3;
    int l = t & 7;
    if (r >= NN) return;
    int beg = rowptr[r];
    int end = rowptr[r + 1];
    float4 acc = make_float4(0.f, 0.f, 0.f, 0.f);
    for (int base = beg; base < end; base += 8) {
        int idx = base + l;
        int sid = (idx < end) ? csr[idx] : 0;
        int n = end - base; if (n > 8) n = 8;
        for (int j = 0; j < n; j++) {
            int s = __shfl(sid, j, 8);
            float4 m = msg[s * 8 + l];
            acc.x += m.x; acc.y += m.y; acc.z += m.z; acc.w += m.w;
        }
    }
    float scd = nd[r];
    float4 o;
    if (L1) {
        float4 bb = ((const float4*)b1)[l];
        float scs = ns[r];
        o.x = fmaxf(scd * acc.x + bb.x, 0.f) * scs;
        o.y = fmaxf(scd * acc.y + bb.y, 0.f) * scs;
        o.z = fmaxf(scd * acc.z + bb.z, 0.f) * scs;
        o.w = fmaxf(scd * acc.w + bb.w, 0.f) * scs;
    } else {
        o.x = scd * acc.x; o.y = scd * acc.y; o.z = scd * acc.z; o.w = scd * acc.w;
    }
    out[r * 8 + l] = o;
}

// ---------------- epilogue: h2 = agg2s@W2 + b2 (agg2s pre-scaled by nd); mu/sigma/z ----------------
__global__ __launch_bounds__(256) void k_final(const float* __restrict__ agg2s,
                                               const float* __restrict__ W2,
                                               const float* __restrict__ b2,
                                               const float* __restrict__ eps,
                                               float* __restrict__ out_mu,
                                               float* __restrict__ out_sigma,
                                               float* __restrict__ z) {
    __shared__ float sW[DE * 64];
    __shared__ float sA[4][DE];
    __shared__ float sMu[4][DE];
    int t = threadIdx.x;
    for (int i = t; i < DE * 64; i += 256) sW[i] = W2[i];
    int rr = t >> 6;
    int c  = t & 63;
    int r  = blockIdx.x * 4 + rr;
    if (c < DE) sA[rr][c] = agg2s[r * DE + c];
    __syncthreads();
    float acc = b2[c];
#pragma unroll
    for (int k = 0; k < DE; k++) acc += sA[rr][k] * sW[k * 64 + c];
    if (c < DE) {
        out_mu[r * DE + c] = acc;
        sMu[rr][c] = acc;
    }
    __syncthreads();
    if (c >= DE) {
        int cc = c - DE;
        float sg = expf(0.5f * acc);
        out_sigma[r * DE + cc] = sg;
        z[r * DE + cc] = sMu[rr][cc] + sg * eps[r * DE + cc];
    }
}

// ---------------- edge dot ----------------
__global__ __launch_bounds__(256) void k_dot(const float* __restrict__ z,
                                             const int* __restrict__ u,
                                             const int* __restrict__ v,
                                             float* __restrict__ out) {
    int t = blockIdx.x * 256 + threadIdx.x;
    int e = t >> 3;
    int l = t & 7;
    if (e < NEP) {
        int a = u[e];
        int b = v[e];
        float4 za = ((const float4*)z)[a * 8 + l];
        float4 zb = ((const float4*)z)[b * 8 + l];
        float s = za.x * zb.x + za.y * zb.y + za.z * zb.z + za.w * zb.w;
        s += __shfl_xor(s, 1);
        s += __shfl_xor(s, 2);
        s += __shfl_xor(s, 4);
        if (l == 0) out[e] = s;
    }
}

extern "C" void kernel_launch(void* const* d_in, const int* in_sizes, int n_in,
                              void* d_out, int out_size, void* d_ws, size_t ws_size,
                              hipStream_t stream) {
    const float* x    = (const float*)d_in[0];
    const float* W1   = (const float*)d_in[1];
    const float* b1   = (const float*)d_in[2];
    const float* W2   = (const float*)d_in[3];
    const float* b2   = (const float*)d_in[4];
    const float* eps  = (const float*)d_in[5];
    const int*   esrc = (const int*)d_in[6];
    const int*   edst = (const int*)d_in[7];
    const int*   psrc = (const int*)d_in[8];
    const int*   pdst = (const int*)d_in[9];
    const int*   gsrc = (const int*)d_in[10];
    const int*   gdst = (const int*)d_in[11];

    float* out = (float*)d_out;
    float* pos = out;                      // [NEP]
    float* neg = out + NEP;                // [NEP]
    float* mu  = out + 2 * NEP;            // [NN*DE]
    float* sg  = out + 2 * NEP + NN * DE;  // [NN*DE]

    // workspace layout (ints then floats; A offset padded to 16B alignment)
    int* wi = (int*)d_ws;
    int* degs   = wi;                 // NN
    int* degd   = degs + NN;          // NN
    int* rowptr = degd + NN;          // NN+1
    int* cursor = rowptr + NN + 1;    // NN
    int* csr    = cursor + NN;        // NE
    float* vns  = (float*)(csr + NE); // NN
    float* vnd  = vns + NN;           // NN
    // pad to 16B alignment for float4 buffers (6*NN+1+NE = 1,900,001 -> 1,900,004)
    float* A    = (float*)((int*)d_ws + 1900004);   // 32*NN: xw1 -> agg2s -> z (aliased)
    float* A2   = A + 32 * NN;                      // 32*NN: h1s
    float* Z    = A;                                // alias (safe: k_final reads/writes same rows per block)

    // zero only the degree histograms
    hipMemsetAsync(degs, 0, (size_t)(2 * NN) * sizeof(int), stream);

    k_deg<<<(NE + 255) / 256, 256, 0, stream>>>(esrc, edst, degs, degd);
    k_norm<<<(NN + 255) / 256, 256, 0, stream>>>(degs, degd, vns, vnd);
    k_scan<<<1, 1024, 0, stream>>>(degd, rowptr, cursor);
    k_fill<<<(NE + 255) / 256, 256, 0, stream>>>(esrc, edst, cursor, csr);
    k_xw1<<<NN / 8, 256, 0, stream>>>(x, W1, vns, A);
    k_gather<true><<<(NN * 8 + 255) / 256, 256, 0, stream>>>(rowptr, csr, (const float4*)A, vnd, b1, vns, (float4*)A2);
    k_gather<false><<<(NN * 8 + 255) / 256, 256, 0, stream>>>(rowptr, csr, (const float4*)A2, vnd, b1, vns, (float4*)A);
    k_final<<<NN / 4, 256, 0, stream>>>(A, W2, b2, eps, mu, sg, Z);
    k_dot<<<(NEP * 8) / 256, 256, 0, stream>>>(Z, psrc, pdst, pos);
    k_dot<<<(NEP * 8) / 256, 256, 0, stream>>>(Z, gsrc, gdst, neg);
}

// Round 3
// 334.913 us; speedup vs baseline: 1.9994x; 1.7983x over previous
//
#include <hip/hip_runtime.h>
#include <math.h>

#define NN  50000
#define NE  1600000
#define NEP 500000
#define DIN 64
#define DE  32

#define BKT_SH 7                 // 128 nodes per bucket
#define NB     391               // ceil(NN / 128)
#define S1B    250               // sort blocks
#define CHK    6400              // NE / S1B

// ---------------- src-degree histogram via LDS privatization ----------------
// 128 blocks x 12500 edges; two node-range halves of 25000 (100 KB LDS each pass).
__global__ __launch_bounds__(256) void k_srchist(const int* __restrict__ src,
                                                 int* __restrict__ degs) {
    __shared__ unsigned int h[25024];
    int t = threadIdx.x;
    int beg = blockIdx.x * (NE / 128);
    for (int half = 0; half < 2; half++) {
        int lo = half * 25000;
        for (int i = t; i < 25024; i += 256) h[i] = 0;
        __syncthreads();
        for (int i = beg + t; i < beg + NE / 128; i += 256) {
            unsigned int rel = (unsigned int)(src[i] - lo);
            if (rel < 25000u) atomicAdd(&h[rel], 1u);
        }
        __syncthreads();
        for (int i = t; i < 25000; i += 256) {
            unsigned int v = h[i];
            if (v) atomicAdd((unsigned int*)&degs[lo + i], v);
        }
        __syncthreads();
    }
}

// ---------------- S1: per-(block,bucket) dst counts ----------------
__global__ __launch_bounds__(256) void k_s1(const int* __restrict__ dst,
                                            int* __restrict__ T) {
    __shared__ int cnt[NB];
    int t = threadIdx.x;
    for (int i = t; i < NB; i += 256) cnt[i] = 0;
    __syncthreads();
    int beg = blockIdx.x * CHK;
    for (int i = beg + t; i < beg + CHK; i += 256)
        atomicAdd(&cnt[dst[i] >> BKT_SH], 1);
    __syncthreads();
    for (int i = t; i < NB; i += 256) T[blockIdx.x * NB + i] = cnt[i];
}

// ---------------- S2: column scan of T -> Base[b][p]; bucket totals -> BS ----------------
__global__ __launch_bounds__(512) void k_s2(const int* __restrict__ T,
                                            int* __restrict__ Base,
                                            int* __restrict__ BS) {
    __shared__ int tot[512];
    int p = threadIdx.x;
    int run = 0;
    if (p < NB) {
        for (int b = 0; b < S1B; b++) {
            Base[b * NB + p] = run;
            run += T[b * NB + p];
        }
    }
    tot[p] = (p < NB) ? run : 0;
    __syncthreads();
    for (int off = 1; off < 512; off <<= 1) {
        int v = (p >= off) ? tot[p - off] : 0;
        __syncthreads();
        tot[p] += v;
        __syncthreads();
    }
    if (p < NB) BS[p] = (p == 0) ? 0 : tot[p - 1];
    if (p == 0) BS[NB] = NE;
}

// ---------------- S3: block-local counting sort by bucket; coalesced pair writes ----------------
__global__ __launch_bounds__(512) void k_s3(const int* __restrict__ src,
                                            const int* __restrict__ dst,
                                            const int* __restrict__ Base,
                                            const int* __restrict__ BS,
                                            uint2* __restrict__ tmp) {
    __shared__ int cnt[NB];
    __shared__ int scn[512];
    __shared__ int delta[NB];
    __shared__ int cur[NB];
    __shared__ uint2 buf[CHK];          // 51.2 KB
    int t = threadIdx.x;
    int beg = blockIdx.x * CHK;
    for (int i = t; i < NB; i += 512) cnt[i] = 0;
    __syncthreads();
    for (int i = t; i < CHK; i += 512)
        atomicAdd(&cnt[dst[beg + i] >> BKT_SH], 1);
    __syncthreads();
    scn[t] = (t < NB) ? cnt[t] : 0;
    __syncthreads();
    for (int off = 1; off < 512; off <<= 1) {
        int v = (t >= off) ? scn[t - off] : 0;
        __syncthreads();
        scn[t] += v;
        __syncthreads();
    }
    if (t < NB) {
        int ls = (t == 0) ? 0 : scn[t - 1];
        cur[t] = ls;
        delta[t] = Base[blockIdx.x * NB + t] + BS[t] - ls;
    }
    __syncthreads();
    for (int i = t; i < CHK; i += 512) {
        int d = dst[beg + i];
        int s = src[beg + i];
        int lp = atomicAdd(&cur[d >> BKT_SH], 1);
        buf[lp] = make_uint2((unsigned)s, (unsigned)d);
    }
    __syncthreads();
    for (int i = t; i < CHK; i += 512) {
        uint2 e = buf[i];
        tmp[delta[e.y >> BKT_SH] + i] = e;
    }
}

// ---------------- S4: per-bucket CSR build (rowptr + csr), all-LDS ----------------
__global__ __launch_bounds__(256) void k_s4(const uint2* __restrict__ tmp,
                                            const int* __restrict__ BS,
                                            int* __restrict__ csr,
                                            int* __restrict__ rowptr) {
    __shared__ int cnt[128];
    __shared__ int scn[128];
    __shared__ int cur[128];
    __shared__ int srcbuf[8192];        // bucket mean 4096, sd 64 -> safe
    int p = blockIdx.x;
    int t = threadIdx.x;
    int ebeg = BS[p], eend = BS[p + 1];
    int ne = eend - ebeg;
    int nodeBeg = p << BKT_SH;
    if (t < 128) cnt[t] = 0;
    __syncthreads();
    for (int i = t; i < ne; i += 256)
        atomicAdd(&cnt[tmp[ebeg + i].y - nodeBeg], 1);
    __syncthreads();
    if (t < 128) scn[t] = cnt[t];
    __syncthreads();
    for (int off = 1; off < 128; off <<= 1) {
        int v = 0;
        if (t < 128 && t >= off) v = scn[t - off];
        __syncthreads();
        if (t < 128) scn[t] += v;
        __syncthreads();
    }
    if (t < 128) {
        int ex = (t == 0) ? 0 : scn[t - 1];
        cur[t] = ex;
        int node = nodeBeg + t;
        if (node < NN) rowptr[node] = ebeg + ex;
    }
    if (p == NB - 1 && t == 0) rowptr[NN] = NE;
    __syncthreads();
    for (int i = t; i < ne; i += 256) {
        uint2 e = tmp[ebeg + i];
        int lp = atomicAdd(&cur[e.y - nodeBeg], 1);
        srcbuf[lp] = (int)e.x;
    }
    __syncthreads();
    for (int i = t; i < ne; i += 256)
        csr[ebeg + i] = srcbuf[i];
}

// ---------------- norms: ns from degs, nd from rowptr diff ----------------
__global__ __launch_bounds__(256) void k_norm(const int* __restrict__ degs,
                                              const int* __restrict__ rowptr,
                                              float* __restrict__ ns,
                                              float* __restrict__ nd) {
    int i = blockIdx.x * 256 + threadIdx.x;
    if (i < NN) {
        ns[i] = rsqrtf(fmaxf((float)degs[i], 1.0f));
        nd[i] = rsqrtf(fmaxf((float)(rowptr[i + 1] - rowptr[i]), 1.0f));
    }
}

// ---------------- xw1[r][c] = ns[r] * (x[r] @ W1)[c] ----------------
__global__ __launch_bounds__(256) void k_xw1(const float* __restrict__ x,
                                             const float* __restrict__ W1,
                                             const float* __restrict__ ns,
                                             float* __restrict__ xw1) {
    __shared__ float sW[DIN * DE];
    int t = threadIdx.x;
    for (int i = t; i < DIN * DE; i += 256) sW[i] = W1[i];
    __syncthreads();
    int r = blockIdx.x * 8 + (t >> 5);
    int c = t & 31;
    const float* xr = x + (size_t)r * DIN;
    float acc = 0.f;
#pragma unroll
    for (int k = 0; k < DIN; k++) acc += xr[k] * sW[k * DE + c];
    xw1[r * DE + c] = acc * ns[r];
}

// ---------------- CSR gather ----------------
template <bool L1>
__global__ __launch_bounds__(256) void k_gather(const int* __restrict__ rowptr,
                                                const int* __restrict__ csr,
                                                const float4* __restrict__ msg,
                                                const float* __restrict__ nd,
                                                const float* __restrict__ b1,
                                                const float* __restrict__ ns,
                                                float4* __restrict__ out) {
    int t = blockIdx.x * 256 + threadIdx.x;
    int r = t >> 3;
    int l = t & 7;
    if (r >= NN) return;
    int beg = rowptr[r];
    int end = rowptr[r + 1];
    float4 acc = make_float4(0.f, 0.f, 0.f, 0.f);
    for (int base = beg; base < end; base += 8) {
        int idx = base + l;
        int sid = (idx < end) ? csr[idx] : 0;
        int n = end - base; if (n > 8) n = 8;
        for (int j = 0; j < n; j++) {
            int s = __shfl(sid, j, 8);
            float4 m = msg[s * 8 + l];
            acc.x += m.x; acc.y += m.y; acc.z += m.z; acc.w += m.w;
        }
    }
    float scd = nd[r];
    float4 o;
    if (L1) {
        float4 bb = ((const float4*)b1)[l];
        float scs = ns[r];
        o.x = fmaxf(scd * acc.x + bb.x, 0.f) * scs;
        o.y = fmaxf(scd * acc.y + bb.y, 0.f) * scs;
        o.z = fmaxf(scd * acc.z + bb.z, 0.f) * scs;
        o.w = fmaxf(scd * acc.w + bb.w, 0.f) * scs;
    } else {
        o.x = scd * acc.x; o.y = scd * acc.y; o.z = scd * acc.z; o.w = scd * acc.w;
    }
    out[r * 8 + l] = o;
}

// ---------------- epilogue ----------------
__global__ __launch_bounds__(256) void k_final(const float* __restrict__ agg2s,
                                               const float* __restrict__ W2,
                                               const float* __restrict__ b2,
                                               const float* __restrict__ eps,
                                               float* __restrict__ out_mu,
                                               float* __restrict__ out_sigma,
                                               float* __restrict__ z) {
    __shared__ float sW[DE * 64];
    __shared__ float sA[4][DE];
    __shared__ float sMu[4][DE];
    int t = threadIdx.x;
    for (int i = t; i < DE * 64; i += 256) sW[i] = W2[i];
    int rr = t >> 6;
    int c  = t & 63;
    int r  = blockIdx.x * 4 + rr;
    if (c < DE) sA[rr][c] = agg2s[r * DE + c];
    __syncthreads();
    float acc = b2[c];
#pragma unroll
    for (int k = 0; k < DE; k++) acc += sA[rr][k] * sW[k * 64 + c];
    if (c < DE) {
        out_mu[r * DE + c] = acc;
        sMu[rr][c] = acc;
    }
    __syncthreads();
    if (c >= DE) {
        int cc = c - DE;
        float sg = expf(0.5f * acc);
        out_sigma[r * DE + cc] = sg;
        z[r * DE + cc] = sMu[rr][cc] + sg * eps[r * DE + cc];
    }
}

// ---------------- edge dot ----------------
__global__ __launch_bounds__(256) void k_dot(const float* __restrict__ z,
                                             const int* __restrict__ u,
                                             const int* __restrict__ v,
                                             float* __restrict__ out) {
    int t = blockIdx.x * 256 + threadIdx.x;
    int e = t >> 3;
    int l = t & 7;
    if (e < NEP) {
        int a = u[e];
        int b = v[e];
        float4 za = ((const float4*)z)[a * 8 + l];
        float4 zb = ((const float4*)z)[b * 8 + l];
        float s = za.x * zb.x + za.y * zb.y + za.z * zb.z + za.w * zb.w;
        s += __shfl_xor(s, 1);
        s += __shfl_xor(s, 2);
        s += __shfl_xor(s, 4);
        if (l == 0) out[e] = s;
    }
}

extern "C" void kernel_launch(void* const* d_in, const int* in_sizes, int n_in,
                              void* d_out, int out_size, void* d_ws, size_t ws_size,
                              hipStream_t stream) {
    const float* x    = (const float*)d_in[0];
    const float* W1   = (const float*)d_in[1];
    const float* b1   = (const float*)d_in[2];
    const float* W2   = (const float*)d_in[3];
    const float* b2   = (const float*)d_in[4];
    const float* eps  = (const float*)d_in[5];
    const int*   esrc = (const int*)d_in[6];
    const int*   edst = (const int*)d_in[7];
    const int*   psrc = (const int*)d_in[8];
    const int*   pdst = (const int*)d_in[9];
    const int*   gsrc = (const int*)d_in[10];
    const int*   gdst = (const int*)d_in[11];

    float* out = (float*)d_out;
    float* pos = out;
    float* neg = out + NEP;
    float* mu  = out + 2 * NEP;
    float* sg  = out + 2 * NEP + NN * DE;

    // workspace layout (ints):
    int* wi     = (int*)d_ws;
    int* degs   = wi;                        // NN
    int* rowptr = degs + NN;                 // NN+1
    int* T      = rowptr + NN + 1;           // S1B*NB = 97750
    int* Base   = T + S1B * NB;              // 97750
    int* BS     = Base + S1B * NB;           // NB+1
    int* csr    = BS + NB + 1;               // NE
    float* vns  = (float*)(csr + NE);        // NN
    float* vnd  = vns + NN;                  // NN
    // 16B-aligned float4 region; tmp (2*NE ints = 12.8MB) aliases A+A2 exactly
    int pad_ofs = ((int)(8 * NN + 1 + 2 * S1B * NB + NB + 1 + NE) + 3) & ~3;
    float* A    = (float*)(wi + pad_ofs);    // 32*NN floats
    float* A2   = A + 32 * NN;               // 32*NN floats
    uint2* tmp  = (uint2*)A;                 // 2*NE ints == 64*NN ints (dead before k_xw1)
    float* Z    = A;

    hipMemsetAsync(degs, 0, (size_t)NN * sizeof(int), stream);

    k_srchist<<<128, 256, 0, stream>>>(esrc, degs);
    k_s1<<<S1B, 256, 0, stream>>>(edst, T);
    k_s2<<<1, 512, 0, stream>>>(T, Base, BS);
    k_s3<<<S1B, 512, 0, stream>>>(esrc, edst, Base, BS, tmp);
    k_s4<<<NB, 256, 0, stream>>>(tmp, BS, csr, rowptr);
    k_norm<<<(NN + 255) / 256, 256, 0, stream>>>(degs, rowptr, vns, vnd);
    k_xw1<<<NN / 8, 256, 0, stream>>>(x, W1, vns, A);
    k_gather<true><<<(NN * 8 + 255) / 256, 256, 0, stream>>>(rowptr, csr, (const float4*)A, vnd, b1, vns, (float4*)A2);
    k_gather<false><<<(NN * 8 + 255) / 256, 256, 0, stream>>>(rowptr, csr, (const float4*)A2, vnd, b1, vns, (float4*)A);
    k_final<<<NN / 4, 256, 0, stream>>>(A, W2, b2, eps, mu, sg, Z);
    k_dot<<<(NEP * 8) / 256, 256, 0, stream>>>(Z, psrc, pdst, pos);
    k_dot<<<(NEP * 8) / 256, 256, 0, stream>>>(Z, gsrc, gdst, neg);
}

// Round 4
// 282.197 us; speedup vs baseline: 2.3729x; 1.1868x over previous
//
#include <hip/hip_runtime.h>
#include <math.h>

#define NN  50000
#define NE  1600000
#define NEP 500000
#define DIN 64
#define DE  32

#define BKT_SH 7                 // 128 nodes per bucket
#define NB     391               // ceil(NN / 128)
#define S1B    250               // sort blocks
#define CHK    6400              // NE / S1B

// ---------------- S1: per-(block,bucket) counts for BOTH dst and src ----------------
__global__ __launch_bounds__(256) void k_s1x(const int* __restrict__ src,
                                             const int* __restrict__ dst,
                                             int* __restrict__ T,
                                             int* __restrict__ T2) {
    __shared__ int cd[NB];
    __shared__ int cs[NB];
    int t = threadIdx.x;
    for (int i = t; i < NB; i += 256) { cd[i] = 0; cs[i] = 0; }
    __syncthreads();
    int beg = blockIdx.x * CHK;
    for (int i = beg + t; i < beg + CHK; i += 256) {
        atomicAdd(&cd[dst[i] >> BKT_SH], 1);
        atomicAdd(&cs[src[i] >> BKT_SH], 1);
    }
    __syncthreads();
    for (int i = t; i < NB; i += 256) {
        T[blockIdx.x * NB + i]  = cd[i];
        T2[blockIdx.x * NB + i] = cs[i];
    }
}

// ---------------- S2: column scan (in place: T becomes Base); 2 blocks (dst, src) ----------------
__global__ __launch_bounds__(512) void k_s2x(int* __restrict__ T,
                                             int* __restrict__ T2,
                                             int* __restrict__ BS,
                                             int* __restrict__ BS2) {
    int* Tp  = blockIdx.x ? T2 : T;
    int* BSp = blockIdx.x ? BS2 : BS;
    __shared__ int tot[512];
    int p = threadIdx.x;
    int run = 0;
    if (p < NB) {
        for (int b = 0; b < S1B; b++) {
            int v = Tp[b * NB + p];
            Tp[b * NB + p] = run;      // in-place: count -> base
            run += v;
        }
    }
    tot[p] = (p < NB) ? run : 0;
    __syncthreads();
    for (int off = 1; off < 512; off <<= 1) {
        int v = (p >= off) ? tot[p - off] : 0;
        __syncthreads();
        tot[p] += v;
        __syncthreads();
    }
    if (p < NB) BSp[p] = (p == 0) ? 0 : tot[p - 1];
    if (p == 0) BSp[NB] = NE;
}

// ---------------- S3: dst-keyed block-local sort; coalesced (src,dst) pair writes ----------------
__global__ __launch_bounds__(512) void k_s3(const int* __restrict__ src,
                                            const int* __restrict__ dst,
                                            const int* __restrict__ Base,
                                            const int* __restrict__ BS,
                                            uint2* __restrict__ tmp) {
    __shared__ int cnt[NB];
    __shared__ int scn[512];
    __shared__ int delta[NB];
    __shared__ int cur[NB];
    __shared__ uint2 buf[CHK];
    int t = threadIdx.x;
    int beg = blockIdx.x * CHK;
    for (int i = t; i < NB; i += 512) cnt[i] = 0;
    __syncthreads();
    for (int i = t; i < CHK; i += 512)
        atomicAdd(&cnt[dst[beg + i] >> BKT_SH], 1);
    __syncthreads();
    scn[t] = (t < NB) ? cnt[t] : 0;
    __syncthreads();
    for (int off = 1; off < 512; off <<= 1) {
        int v = (t >= off) ? scn[t - off] : 0;
        __syncthreads();
        scn[t] += v;
        __syncthreads();
    }
    if (t < NB) {
        int ls = (t == 0) ? 0 : scn[t - 1];
        cur[t] = ls;
        delta[t] = Base[blockIdx.x * NB + t] + BS[t] - ls;
    }
    __syncthreads();
    for (int i = t; i < CHK; i += 512) {
        int d = dst[beg + i];
        int s = src[beg + i];
        int lp = atomicAdd(&cur[d >> BKT_SH], 1);
        buf[lp] = make_uint2((unsigned)s, (unsigned)d);
    }
    __syncthreads();
    for (int i = t; i < CHK; i += 512) {
        uint2 e = buf[i];
        tmp[delta[e.y >> BKT_SH] + i] = e;
    }
}

// ---------------- S3s: src-keyed block-local sort; values only ----------------
__global__ __launch_bounds__(512) void k_s3s(const int* __restrict__ src,
                                             const int* __restrict__ Base2,
                                             const int* __restrict__ BS2,
                                             int* __restrict__ tmp2) {
    __shared__ int cnt[NB];
    __shared__ int scn[512];
    __shared__ int delta[NB];
    __shared__ int cur[NB];
    __shared__ int buf[CHK];
    int t = threadIdx.x;
    int beg = blockIdx.x * CHK;
    for (int i = t; i < NB; i += 512) cnt[i] = 0;
    __syncthreads();
    for (int i = t; i < CHK; i += 512)
        atomicAdd(&cnt[src[beg + i] >> BKT_SH], 1);
    __syncthreads();
    scn[t] = (t < NB) ? cnt[t] : 0;
    __syncthreads();
    for (int off = 1; off < 512; off <<= 1) {
        int v = (t >= off) ? scn[t - off] : 0;
        __syncthreads();
        scn[t] += v;
        __syncthreads();
    }
    if (t < NB) {
        int ls = (t == 0) ? 0 : scn[t - 1];
        cur[t] = ls;
        delta[t] = Base2[blockIdx.x * NB + t] + BS2[t] - ls;
    }
    __syncthreads();
    for (int i = t; i < CHK; i += 512) {
        int s = src[beg + i];
        int lp = atomicAdd(&cur[s >> BKT_SH], 1);
        buf[lp] = s;
    }
    __syncthreads();
    for (int i = t; i < CHK; i += 512) {
        int s = buf[i];
        tmp2[delta[s >> BKT_SH] + i] = s;
    }
}

// ---------------- S4x: per-bucket CSR build + src-degree histogram (all coalesced writes) ----------------
__global__ __launch_bounds__(256) void k_s4x(const uint2* __restrict__ tmp,
                                             const int* __restrict__ BS,
                                             const int* __restrict__ tmp2,
                                             const int* __restrict__ BS2,
                                             int* __restrict__ csr,
                                             int* __restrict__ rowptr,
                                             int* __restrict__ degs) {
    __shared__ int cnt[128];
    __shared__ int cnt2[128];
    __shared__ int scn[128];
    __shared__ int cur[128];
    __shared__ int srcbuf[8192];        // bucket mean 4096, sd 64 -> safe
    int p = blockIdx.x;
    int t = threadIdx.x;
    int nodeBeg = p << BKT_SH;
    if (t < 128) { cnt[t] = 0; cnt2[t] = 0; }
    __syncthreads();
    // src-degree histogram over this bucket's sorted src ids
    int sb = BS2[p], se = BS2[p + 1];
    for (int i = sb + t; i < se; i += 256)
        atomicAdd(&cnt2[tmp2[i] - nodeBeg], 1);
    // dst histogram
    int ebeg = BS[p], eend = BS[p + 1];
    int ne = eend - ebeg;
    for (int i = t; i < ne; i += 256)
        atomicAdd(&cnt[tmp[ebeg + i].y - nodeBeg], 1);
    __syncthreads();
    if (t < 128) {
        int node = nodeBeg + t;
        if (node < NN) degs[node] = cnt2[t];   // coalesced, non-atomic
        scn[t] = cnt[t];
    }
    __syncthreads();
    for (int off = 1; off < 128; off <<= 1) {
        int v = 0;
        if (t < 128 && t >= off) v = scn[t - off];
        __syncthreads();
        if (t < 128) scn[t] += v;
        __syncthreads();
    }
    if (t < 128) {
        int ex = (t == 0) ? 0 : scn[t - 1];
        cur[t] = ex;
        int node = nodeBeg + t;
        if (node < NN) rowptr[node] = ebeg + ex;
    }
    if (p == NB - 1 && t == 0) rowptr[NN] = NE;
    __syncthreads();
    for (int i = t; i < ne; i += 256) {
        uint2 e = tmp[ebeg + i];
        int lp = atomicAdd(&cur[e.y - nodeBeg], 1);
        srcbuf[lp] = (int)e.x;
    }
    __syncthreads();
    for (int i = t; i < ne; i += 256)
        csr[ebeg + i] = srcbuf[i];
}

// ---------------- xw1[r][c] = ns[r] * (x[r] @ W1)[c]; ns inline from degs ----------------
__global__ __launch_bounds__(256) void k_xw1(const float* __restrict__ x,
                                             const float* __restrict__ W1,
                                             const int* __restrict__ degs,
                                             float* __restrict__ xw1) {
    __shared__ float sW[DIN * DE];
    int t = threadIdx.x;
    for (int i = t; i < DIN * DE; i += 256) sW[i] = W1[i];
    __syncthreads();
    int r = blockIdx.x * 8 + (t >> 5);
    int c = t & 31;
    const float* xr = x + (size_t)r * DIN;
    float acc = 0.f;
#pragma unroll
    for (int k = 0; k < DIN; k++) acc += xr[k] * sW[k * DE + c];
    xw1[r * DE + c] = acc * rsqrtf(fmaxf((float)degs[r], 1.0f));
}

// ---------------- CSR gather; nd from rowptr diff, ns from degs (L1 only) ----------------
template <bool L1>
__global__ __launch_bounds__(256) void k_gather(const int* __restrict__ rowptr,
                                                const int* __restrict__ csr,
                                                const float4* __restrict__ msg,
                                                const int* __restrict__ degs,
                                                const float* __restrict__ b1,
                                                float4* __restrict__ out) {
    int t = blockIdx.x * 256 + threadIdx.x;
    int r = t >> 3;
    int l = t & 7;
    if (r >= NN) return;
    int beg = rowptr[r];
    int end = rowptr[r + 1];
    float4 acc = make_float4(0.f, 0.f, 0.f, 0.f);
    for (int base = beg; base < end; base += 8) {
        int idx = base + l;
        int sid = (idx < end) ? csr[idx] : 0;
        int n = end - base; if (n > 8) n = 8;
        for (int j = 0; j < n; j++) {
            int s = __shfl(sid, j, 8);
            float4 m = msg[s * 8 + l];
            acc.x += m.x; acc.y += m.y; acc.z += m.z; acc.w += m.w;
        }
    }
    float scd = rsqrtf(fmaxf((float)(end - beg), 1.0f));
    float4 o;
    if (L1) {
        float4 bb = ((const float4*)b1)[l];
        float scs = rsqrtf(fmaxf((float)degs[r], 1.0f));
        o.x = fmaxf(scd * acc.x + bb.x, 0.f) * scs;
        o.y = fmaxf(scd * acc.y + bb.y, 0.f) * scs;
        o.z = fmaxf(scd * acc.z + bb.z, 0.f) * scs;
        o.w = fmaxf(scd * acc.w + bb.w, 0.f) * scs;
    } else {
        o.x = scd * acc.x; o.y = scd * acc.y; o.z = scd * acc.z; o.w = scd * acc.w;
    }
    out[r * 8 + l] = o;
}

// ---------------- epilogue ----------------
__global__ __launch_bounds__(256) void k_final(const float* __restrict__ agg2s,
                                               const float* __restrict__ W2,
                                               const float* __restrict__ b2,
                                               const float* __restrict__ eps,
                                               float* __restrict__ out_mu,
                                               float* __restrict__ out_sigma,
                                               float* __restrict__ z) {
    __shared__ float sW[DE * 64];
    __shared__ float sA[4][DE];
    __shared__ float sMu[4][DE];
    int t = threadIdx.x;
    for (int i = t; i < DE * 64; i += 256) sW[i] = W2[i];
    int rr = t >> 6;
    int c  = t & 63;
    int r  = blockIdx.x * 4 + rr;
    if (c < DE) sA[rr][c] = agg2s[r * DE + c];
    __syncthreads();
    float acc = b2[c];
#pragma unroll
    for (int k = 0; k < DE; k++) acc += sA[rr][k] * sW[k * 64 + c];
    if (c < DE) {
        out_mu[r * DE + c] = acc;
        sMu[rr][c] = acc;
    }
    __syncthreads();
    if (c >= DE) {
        int cc = c - DE;
        float sg = expf(0.5f * acc);
        out_sigma[r * DE + cc] = sg;
        z[r * DE + cc] = sMu[rr][cc] + sg * eps[r * DE + cc];
    }
}

// ---------------- merged edge dot (pos then neg) ----------------
__global__ __launch_bounds__(256) void k_dot2(const float* __restrict__ z,
                                              const int* __restrict__ pu,
                                              const int* __restrict__ pv,
                                              const int* __restrict__ nu,
                                              const int* __restrict__ nv,
                                              float* __restrict__ out) {
    int t = blockIdx.x * 256 + threadIdx.x;
    int e = t >> 3;
    int l = t & 7;
    if (e < 2 * NEP) {
        int ee = (e < NEP) ? e : e - NEP;
        const int* uu = (e < NEP) ? pu : nu;
        const int* vv = (e < NEP) ? pv : nv;
        int a = uu[ee];
        int b = vv[ee];
        float4 za = ((const float4*)z)[a * 8 + l];
        float4 zb = ((const float4*)z)[b * 8 + l];
        float s = za.x * zb.x + za.y * zb.y + za.z * zb.z + za.w * zb.w;
        s += __shfl_xor(s, 1);
        s += __shfl_xor(s, 2);
        s += __shfl_xor(s, 4);
        if (l == 0) out[e] = s;
    }
}

extern "C" void kernel_launch(void* const* d_in, const int* in_sizes, int n_in,
                              void* d_out, int out_size, void* d_ws, size_t ws_size,
                              hipStream_t stream) {
    const float* x    = (const float*)d_in[0];
    const float* W1   = (const float*)d_in[1];
    const float* b1   = (const float*)d_in[2];
    const float* W2   = (const float*)d_in[3];
    const float* b2   = (const float*)d_in[4];
    const float* eps  = (const float*)d_in[5];
    const int*   esrc = (const int*)d_in[6];
    const int*   edst = (const int*)d_in[7];
    const int*   psrc = (const int*)d_in[8];
    const int*   pdst = (const int*)d_in[9];
    const int*   gsrc = (const int*)d_in[10];
    const int*   gdst = (const int*)d_in[11];

    float* out = (float*)d_out;
    float* pos = out;
    float* mu  = out + 2 * NEP;
    float* sg  = out + 2 * NEP + NN * DE;

    // workspace layout (ints):
    int* wi     = (int*)d_ws;
    int* rowptr = wi;                        // NN+1
    int* T      = rowptr + NN + 1;           // S1B*NB (becomes Base in-place)
    int* T2     = T + S1B * NB;              // S1B*NB (becomes Base2 in-place)
    int* BS     = T2 + S1B * NB;             // NB+1
    int* BS2    = BS + NB + 1;               // NB+1
    int* degs   = BS2 + NB + 1;              // NN
    int* csr    = degs + NN;                 // NE
    int* tmp2   = csr + NE;                  // NE
    // 16B-aligned float region; tmp (2*NE ints) aliases A+A2 exactly (dead before k_xw1)
    size_t used = (size_t)(NN + 1) + 2 * S1B * NB + 2 * (NB + 1) + NN + 2 * (size_t)NE;
    size_t pad_ofs = (used + 3) & ~(size_t)3;
    float* A    = (float*)(wi + pad_ofs);    // 32*NN floats
    float* A2   = A + 32 * NN;               // 32*NN floats
    uint2* tmp  = (uint2*)A;
    float* Z    = A;

    k_s1x<<<S1B, 256, 0, stream>>>(esrc, edst, T, T2);
    k_s2x<<<2, 512, 0, stream>>>(T, T2, BS, BS2);
    k_s3<<<S1B, 512, 0, stream>>>(esrc, edst, T, BS, tmp);
    k_s3s<<<S1B, 512, 0, stream>>>(esrc, T2, BS2, tmp2);
    k_s4x<<<NB, 256, 0, stream>>>(tmp, BS, tmp2, BS2, csr, rowptr, degs);
    k_xw1<<<NN / 8, 256, 0, stream>>>(x, W1, degs, A);
    k_gather<true><<<(NN * 8 + 255) / 256, 256, 0, stream>>>(rowptr, csr, (const float4*)A, degs, b1, (float4*)A2);
    k_gather<false><<<(NN * 8 + 255) / 256, 256, 0, stream>>>(rowptr, csr, (const float4*)A2, degs, b1, (float4*)A);
    k_final<<<NN / 4, 256, 0, stream>>>(A, W2, b2, eps, mu, sg, Z);
    k_dot2<<<(2 * NEP * 8) / 256, 256, 0, stream>>>(Z, psrc, pdst, gsrc, gdst, pos);
}

// Round 5
// 250.123 us; speedup vs baseline: 2.6772x; 1.1282x over previous
//
#include <hip/hip_runtime.h>
#include <math.h>

#define NN  50000
#define NE  1600000
#define NEP 500000
#define DIN 64
#define DE  32

#define BKT_SH 7                 // 128 nodes per bucket
#define NB     391               // ceil(NN / 128)
#define S1B    250               // sort blocks
#define CHK    6400              // NE / S1B

// ---------------- bf16 pack/unpack helpers (RNE) ----------------
__device__ __forceinline__ unsigned f2b(float f) {
    unsigned u = __float_as_uint(f);
    return (u + 0x7FFFu + ((u >> 16) & 1u)) >> 16;
}
__device__ __forceinline__ unsigned pack2(float a, float b) {
    return f2b(a) | (f2b(b) << 16);
}
__device__ __forceinline__ float blo(unsigned u) { return __uint_as_float(u << 16); }
__device__ __forceinline__ float bhi(unsigned u) { return __uint_as_float(u & 0xFFFF0000u); }

// ---------------- S1: per-(block,bucket) counts for BOTH dst and src ----------------
__global__ __launch_bounds__(256) void k_s1x(const int* __restrict__ src,
                                             const int* __restrict__ dst,
                                             int* __restrict__ T,
                                             int* __restrict__ T2) {
    __shared__ int cd[NB];
    __shared__ int cs[NB];
    int t = threadIdx.x;
    for (int i = t; i < NB; i += 256) { cd[i] = 0; cs[i] = 0; }
    __syncthreads();
    int beg = blockIdx.x * CHK;
    for (int i = beg + t; i < beg + CHK; i += 256) {
        atomicAdd(&cd[dst[i] >> BKT_SH], 1);
        atomicAdd(&cs[src[i] >> BKT_SH], 1);
    }
    __syncthreads();
    for (int i = t; i < NB; i += 256) {
        T[blockIdx.x * NB + i]  = cd[i];
        T2[blockIdx.x * NB + i] = cs[i];
    }
}

// ---------------- S2: column scan (in place: T becomes Base); 2 blocks ----------------
__global__ __launch_bounds__(512) void k_s2x(int* __restrict__ T,
                                             int* __restrict__ T2,
                                             int* __restrict__ BS,
                                             int* __restrict__ BS2) {
    int* Tp  = blockIdx.x ? T2 : T;
    int* BSp = blockIdx.x ? BS2 : BS;
    __shared__ int tot[512];
    int p = threadIdx.x;
    int run = 0;
    if (p < NB) {
        for (int b = 0; b < S1B; b++) {
            int v = Tp[b * NB + p];
            Tp[b * NB + p] = run;
            run += v;
        }
    }
    tot[p] = (p < NB) ? run : 0;
    __syncthreads();
    for (int off = 1; off < 512; off <<= 1) {
        int v = (p >= off) ? tot[p - off] : 0;
        __syncthreads();
        tot[p] += v;
        __syncthreads();
    }
    if (p < NB) BSp[p] = (p == 0) ? 0 : tot[p - 1];
    if (p == 0) BSp[NB] = NE;
}

// ---------------- S3m: merged dst-keyed pair sort + src-keyed value sort ----------------
__global__ __launch_bounds__(512) void k_s3m(const int* __restrict__ src,
                                             const int* __restrict__ dst,
                                             const int* __restrict__ Base,
                                             const int* __restrict__ BS,
                                             const int* __restrict__ Base2,
                                             const int* __restrict__ BS2,
                                             uint2* __restrict__ tmp,
                                             int* __restrict__ tmp2) {
    __shared__ int cnt[NB];
    __shared__ int scn[512];
    __shared__ int delta[NB];
    __shared__ int cur[NB];
    __shared__ uint2 buf[CHK];          // 51.2 KB, reused as int buf in src phase
    int* bufi = (int*)buf;
    int t = threadIdx.x;
    int beg = blockIdx.x * CHK;
    // ---- dst phase: emit (src,dst) pairs bucket-major ----
    for (int i = t; i < NB; i += 512) cnt[i] = 0;
    __syncthreads();
    for (int i = t; i < CHK; i += 512)
        atomicAdd(&cnt[dst[beg + i] >> BKT_SH], 1);
    __syncthreads();
    scn[t] = (t < NB) ? cnt[t] : 0;
    __syncthreads();
    for (int off = 1; off < 512; off <<= 1) {
        int v = (t >= off) ? scn[t - off] : 0;
        __syncthreads();
        scn[t] += v;
        __syncthreads();
    }
    if (t < NB) {
        int ls = (t == 0) ? 0 : scn[t - 1];
        cur[t] = ls;
        delta[t] = Base[blockIdx.x * NB + t] + BS[t] - ls;
    }
    __syncthreads();
    for (int i = t; i < CHK; i += 512) {
        int d = dst[beg + i];
        int s = src[beg + i];
        int lp = atomicAdd(&cur[d >> BKT_SH], 1);
        buf[lp] = make_uint2((unsigned)s, (unsigned)d);
    }
    __syncthreads();
    for (int i = t; i < CHK; i += 512) {
        uint2 e = buf[i];
        tmp[delta[e.y >> BKT_SH] + i] = e;
    }
    __syncthreads();
    // ---- src phase: emit src ids bucket-major (for degree histogram) ----
    for (int i = t; i < NB; i += 512) cnt[i] = 0;
    __syncthreads();
    for (int i = t; i < CHK; i += 512)
        atomicAdd(&cnt[src[beg + i] >> BKT_SH], 1);
    __syncthreads();
    scn[t] = (t < NB) ? cnt[t] : 0;
    __syncthreads();
    for (int off = 1; off < 512; off <<= 1) {
        int v = (t >= off) ? scn[t - off] : 0;
        __syncthreads();
        scn[t] += v;
        __syncthreads();
    }
    if (t < NB) {
        int ls = (t == 0) ? 0 : scn[t - 1];
        cur[t] = ls;
        delta[t] = Base2[blockIdx.x * NB + t] + BS2[t] - ls;
    }
    __syncthreads();
    for (int i = t; i < CHK; i += 512) {
        int s = src[beg + i];
        int lp = atomicAdd(&cur[s >> BKT_SH], 1);
        bufi[lp] = s;
    }
    __syncthreads();
    for (int i = t; i < CHK; i += 512) {
        int s = bufi[i];
        tmp2[delta[s >> BKT_SH] + i] = s;
    }
}

// ---------------- S4x: per-bucket CSR build + src-degree histogram ----------------
__global__ __launch_bounds__(256) void k_s4x(const uint2* __restrict__ tmp,
                                             const int* __restrict__ BS,
                                             const int* __restrict__ tmp2,
                                             const int* __restrict__ BS2,
                                             int* __restrict__ csr,
                                             int* __restrict__ rowptr,
                                             int* __restrict__ degs) {
    __shared__ int cnt[128];
    __shared__ int cnt2[128];
    __shared__ int scn[128];
    __shared__ int cur[128];
    __shared__ int srcbuf[8192];
    int p = blockIdx.x;
    int t = threadIdx.x;
    int nodeBeg = p << BKT_SH;
    if (t < 128) { cnt[t] = 0; cnt2[t] = 0; }
    __syncthreads();
    int sb = BS2[p], se = BS2[p + 1];
    for (int i = sb + t; i < se; i += 256)
        atomicAdd(&cnt2[tmp2[i] - nodeBeg], 1);
    int ebeg = BS[p], eend = BS[p + 1];
    int ne = eend - ebeg;
    for (int i = t; i < ne; i += 256)
        atomicAdd(&cnt[tmp[ebeg + i].y - nodeBeg], 1);
    __syncthreads();
    if (t < 128) {
        int node = nodeBeg + t;
        if (node < NN) degs[node] = cnt2[t];
        scn[t] = cnt[t];
    }
    __syncthreads();
    for (int off = 1; off < 128; off <<= 1) {
        int v = 0;
        if (t < 128 && t >= off) v = scn[t - off];
        __syncthreads();
        if (t < 128) scn[t] += v;
        __syncthreads();
    }
    if (t < 128) {
        int ex = (t == 0) ? 0 : scn[t - 1];
        cur[t] = ex;
        int node = nodeBeg + t;
        if (node < NN) rowptr[node] = ebeg + ex;
    }
    if (p == NB - 1 && t == 0) rowptr[NN] = NE;
    __syncthreads();
    for (int i = t; i < ne; i += 256) {
        uint2 e = tmp[ebeg + i];
        int lp = atomicAdd(&cur[e.y - nodeBeg], 1);
        srcbuf[lp] = (int)e.x;
    }
    __syncthreads();
    for (int i = t; i < ne; i += 256)
        csr[ebeg + i] = srcbuf[i];
}

// ---------------- xw1 (bf16 packed out): 16 rows x 16 channel-pairs per block ----------------
__global__ __launch_bounds__(256) void k_xw1(const float* __restrict__ x,
                                             const float* __restrict__ W1,
                                             const int* __restrict__ degs,
                                             unsigned* __restrict__ xw1b) {
    __shared__ float sW[DIN * DE];
    int t = threadIdx.x;
    for (int i = t; i < DIN * DE; i += 256) sW[i] = W1[i];
    __syncthreads();
    int r  = blockIdx.x * 16 + (t >> 4);
    int tc = t & 15;
    const float* xr = x + (size_t)r * DIN;
    float a0 = 0.f, a1 = 0.f;
#pragma unroll
    for (int k = 0; k < DIN; k++) {
        float v = xr[k];
        a0 += v * sW[k * DE + 2 * tc];
        a1 += v * sW[k * DE + 2 * tc + 1];
    }
    float ns = rsqrtf(fmaxf((float)degs[r], 1.0f));
    xw1b[r * 16 + tc] = pack2(a0 * ns, a1 * ns);
}

// ---------------- gather layer 1: bf16 msg -> relu/bias/scale -> bf16 out ----------------
__global__ __launch_bounds__(256) void k_g1(const int* __restrict__ rowptr,
                                            const int* __restrict__ csr,
                                            const uint2* __restrict__ msg,
                                            const int* __restrict__ degs,
                                            const float* __restrict__ b1,
                                            uint2* __restrict__ out) {
    int t = blockIdx.x * 256 + threadIdx.x;
    int r = t >> 3;
    int l = t & 7;
    if (r >= NN) return;
    int beg = rowptr[r];
    int end = rowptr[r + 1];
    float4 acc = make_float4(0.f, 0.f, 0.f, 0.f);
    for (int base = beg; base < end; base += 8) {
        int idx = base + l;
        int sid = (idx < end) ? csr[idx] : 0;
        int n = end - base; if (n > 8) n = 8;
        for (int j = 0; j < n; j++) {
            int s = __shfl(sid, j, 8);
            uint2 w = msg[s * 8 + l];
            acc.x += blo(w.x); acc.y += bhi(w.x);
            acc.z += blo(w.y); acc.w += bhi(w.y);
        }
    }
    float scd = rsqrtf(fmaxf((float)(end - beg), 1.0f));
    float scs = rsqrtf(fmaxf((float)degs[r], 1.0f));
    float4 bb = ((const float4*)b1)[l];
    float ox = fmaxf(scd * acc.x + bb.x, 0.f) * scs;
    float oy = fmaxf(scd * acc.y + bb.y, 0.f) * scs;
    float oz = fmaxf(scd * acc.z + bb.z, 0.f) * scs;
    float ow = fmaxf(scd * acc.w + bb.w, 0.f) * scs;
    out[r * 8 + l] = make_uint2(pack2(ox, oy), pack2(oz, ow));
}

// ---------------- gather layer 2: bf16 msg -> f32 out (nd-scaled) ----------------
__global__ __launch_bounds__(256) void k_g2(const int* __restrict__ rowptr,
                                            const int* __restrict__ csr,
                                            const uint2* __restrict__ msg,
                                            float4* __restrict__ out) {
    int t = blockIdx.x * 256 + threadIdx.x;
    int r = t >> 3;
    int l = t & 7;
    if (r >= NN) return;
    int beg = rowptr[r];
    int end = rowptr[r + 1];
    float4 acc = make_float4(0.f, 0.f, 0.f, 0.f);
    for (int base = beg; base < end; base += 8) {
        int idx = base + l;
        int sid = (idx < end) ? csr[idx] : 0;
        int n = end - base; if (n > 8) n = 8;
        for (int j = 0; j < n; j++) {
            int s = __shfl(sid, j, 8);
            uint2 w = msg[s * 8 + l];
            acc.x += blo(w.x); acc.y += bhi(w.x);
            acc.z += blo(w.y); acc.w += bhi(w.y);
        }
    }
    float scd = rsqrtf(fmaxf((float)(end - beg), 1.0f));
    out[r * 8 + l] = make_float4(scd * acc.x, scd * acc.y, scd * acc.z, scd * acc.w);
}

// ---------------- epilogue: h2 = agg2s@W2 + b2; mu/sigma f32 out, z bf16 packed ----------------
__global__ __launch_bounds__(256) void k_final(const float* __restrict__ agg2s,
                                               const float* __restrict__ W2,
                                               const float* __restrict__ b2,
                                               const float* __restrict__ eps,
                                               float* __restrict__ out_mu,
                                               float* __restrict__ out_sigma,
                                               unsigned* __restrict__ zb) {
    __shared__ float sW[DE * 64];
    __shared__ float sA[4][DE];
    __shared__ float sMu[4][DE];
    __shared__ float sZ[4][DE];
    int t = threadIdx.x;
    for (int i = t; i < DE * 64; i += 256) sW[i] = W2[i];
    int rr = t >> 6;
    int c  = t & 63;
    int r  = blockIdx.x * 4 + rr;
    if (c < DE) sA[rr][c] = agg2s[r * DE + c];
    __syncthreads();
    float acc = b2[c];
#pragma unroll
    for (int k = 0; k < DE; k++) acc += sA[rr][k] * sW[k * 64 + c];
    if (c < DE) {
        out_mu[r * DE + c] = acc;
        sMu[rr][c] = acc;
    }
    __syncthreads();
    if (c >= DE) {
        int cc = c - DE;
        float sg = expf(0.5f * acc);
        out_sigma[r * DE + cc] = sg;
        sZ[rr][cc] = sMu[rr][cc] + sg * eps[r * DE + cc];
    }
    __syncthreads();
    if (t < 64) {
        int r2 = blockIdx.x * 4 + (t >> 4);
        int i  = t & 15;
        zb[r2 * 16 + i] = pack2(sZ[t >> 4][2 * i], sZ[t >> 4][2 * i + 1]);
    }
}

// ---------------- merged edge dot over bf16 z ----------------
__global__ __launch_bounds__(256) void k_dot2(const uint2* __restrict__ zb,
                                              const int* __restrict__ pu,
                                              const int* __restrict__ pv,
                                              const int* __restrict__ nu,
                                              const int* __restrict__ nv,
                                              float* __restrict__ out) {
    int t = blockIdx.x * 256 + threadIdx.x;
    int e = t >> 3;
    int l = t & 7;
    if (e < 2 * NEP) {
        int ee = (e < NEP) ? e : e - NEP;
        const int* uu = (e < NEP) ? pu : nu;
        const int* vv = (e < NEP) ? pv : nv;
        int a = uu[ee];
        int b = vv[ee];
        uint2 za = zb[a * 8 + l];
        uint2 zc = zb[b * 8 + l];
        float s = blo(za.x) * blo(zc.x) + bhi(za.x) * bhi(zc.x)
                + blo(za.y) * blo(zc.y) + bhi(za.y) * bhi(zc.y);
        s += __shfl_xor(s, 1);
        s += __shfl_xor(s, 2);
        s += __shfl_xor(s, 4);
        if (l == 0) out[e] = s;
    }
}

extern "C" void kernel_launch(void* const* d_in, const int* in_sizes, int n_in,
                              void* d_out, int out_size, void* d_ws, size_t ws_size,
                              hipStream_t stream) {
    const float* x    = (const float*)d_in[0];
    const float* W1   = (const float*)d_in[1];
    const float* b1   = (const float*)d_in[2];
    const float* W2   = (const float*)d_in[3];
    const float* b2   = (const float*)d_in[4];
    const float* eps  = (const float*)d_in[5];
    const int*   esrc = (const int*)d_in[6];
    const int*   edst = (const int*)d_in[7];
    const int*   psrc = (const int*)d_in[8];
    const int*   pdst = (const int*)d_in[9];
    const int*   gsrc = (const int*)d_in[10];
    const int*   gdst = (const int*)d_in[11];

    float* out = (float*)d_out;
    float* pos = out;                      // pos[NEP] then neg[NEP] contiguous
    float* mu  = out + 2 * NEP;
    float* sg  = out + 2 * NEP + NN * DE;

    // ---- workspace layout ----
    int* wi     = (int*)d_ws;
    int* rowptr = wi;                        // NN+1
    int* T      = rowptr + NN + 1;           // S1B*NB  (-> Base in place)
    int* T2     = T + S1B * NB;              // S1B*NB  (-> Base2 in place)
    int* BS     = T2 + S1B * NB;             // NB+1
    int* BS2    = BS + NB + 1;               // NB+1
    int* degs   = BS2 + NB + 1;              // NN
    int* csr    = degs + NN;                 // NE
    int* tmp2   = csr + NE;                  // NE
    size_t used = (size_t)(NN + 1) + 2 * (size_t)S1B * NB + 2 * (NB + 1) + NN + 2 * (size_t)NE;
    size_t pad_ofs = (used + 3) & ~(size_t)3;
    // P region (3.2M ints total); tmp (2*NE ints) aliases all of it (dead before k_xw1)
    unsigned* P0 = (unsigned*)(wi + pad_ofs);   // 800000 u32: xw1b, later zb
    unsigned* P1 = P0 + 16 * NN;                // 800000 u32: h1b
    float*    P2 = (float*)(P1 + 16 * NN);      // 1600000 f32: agg2 (f32)
    uint2*    tmp = (uint2*)P0;

    k_s1x<<<S1B, 256, 0, stream>>>(esrc, edst, T, T2);
    k_s2x<<<2, 512, 0, stream>>>(T, T2, BS, BS2);
    k_s3m<<<S1B, 512, 0, stream>>>(esrc, edst, T, BS, T2, BS2, tmp, tmp2);
    k_s4x<<<NB, 256, 0, stream>>>(tmp, BS, tmp2, BS2, csr, rowptr, degs);
    k_xw1<<<NN / 16, 256, 0, stream>>>(x, W1, degs, P0);
    k_g1<<<(NN * 8 + 255) / 256, 256, 0, stream>>>(rowptr, csr, (const uint2*)P0, degs, b1, (uint2*)P1);
    k_g2<<<(NN * 8 + 255) / 256, 256, 0, stream>>>(rowptr, csr, (const uint2*)P1, (float4*)P2);
    k_final<<<NN / 4, 256, 0, stream>>>(P2, W2, b2, eps, mu, sg, P0);
    k_dot2<<<(2 * NEP * 8) / 256, 256, 0, stream>>>((const uint2*)P0, psrc, pdst, gsrc, gdst, pos);
}